// Round 1
// baseline (4115.869 us; speedup 1.0000x reference)
//
#include <hip/hip_runtime.h>
#include <cmath>

#define HIDDEN 256
#define NUM_RADIAL 6
#define OUT_EMB 192
#define NUM_LAYERS 3
#define TN 32

// Kernel 1: per-edge gate (rbf @ W_rbf) * x, scatter-add into xn[node][c]
__global__ __launch_bounds__(256) void edge_scatter(
    const float* __restrict__ x, const float* __restrict__ rbf,
    const int* __restrict__ idx, const float* __restrict__ W_rbf,
    float* __restrict__ xn, int E)
{
    __shared__ float wlds[NUM_RADIAL * HIDDEN];
    for (int t = threadIdx.x; t < NUM_RADIAL * HIDDEN; t += 256)
        wlds[t] = W_rbf[t];
    __syncthreads();

    const int lane = threadIdx.x & 63;
    const int wid  = threadIdx.x >> 6;            // 0..3
    const int gw   = blockIdx.x * 4 + wid;        // global wave id
    const int nw   = gridDim.x * 4;               // total waves
    const int c0   = lane * 4;

    // W_rbf columns for this lane's 4 channels, held in registers
    float wcol[NUM_RADIAL][4];
    #pragma unroll
    for (int r = 0; r < NUM_RADIAL; r++)
        #pragma unroll
        for (int k = 0; k < 4; k++)
            wcol[r][k] = wlds[r * HIDDEN + c0 + k];

    for (int e = gw; e < E; e += nw) {
        const float4 xv = *(const float4*)(x + (long long)e * HIDDEN + c0);
        float rb[NUM_RADIAL];
        #pragma unroll
        for (int r = 0; r < NUM_RADIAL; r++) rb[r] = rbf[(long long)e * NUM_RADIAL + r];
        const int node = idx[e];

        float g0 = 0.f, g1 = 0.f, g2 = 0.f, g3 = 0.f;
        #pragma unroll
        for (int r = 0; r < NUM_RADIAL; r++) {
            g0 += rb[r] * wcol[r][0];
            g1 += rb[r] * wcol[r][1];
            g2 += rb[r] * wcol[r][2];
            g3 += rb[r] * wcol[r][3];
        }
        float* dst = xn + (long long)node * HIDDEN + c0;
        atomicAdd(dst + 0, g0 * xv.x);
        atomicAdd(dst + 1, g1 * xv.y);
        atomicAdd(dst + 2, g2 * xv.z);
        atomicAdd(dst + 3, g3 * xv.w);
    }
}

// Kernel 2: fused node MLP. Block = 192 threads (thread j = column j),
// TN=32 nodes per block. Activations in LDS, wave-uniform broadcast reads.
__global__ __launch_bounds__(192) void node_mlp(
    const float* __restrict__ xn,
    const float* __restrict__ W_up, const float* __restrict__ b_up,
    const float* __restrict__ W_lins, const float* __restrict__ b_lins,
    const float* __restrict__ W_out,
    float* __restrict__ out, int N)
{
    __shared__ float xl[TN * HIDDEN];    // 32 KB
    __shared__ float hl[TN * OUT_EMB];   // 24 KB
    const int j = threadIdx.x;
    const int nbase = blockIdx.x * TN;

    // stage xn tile (zero-pad past N)
    for (int t = j; t < TN * HIDDEN; t += 192) {
        const int n = t / HIDDEN;
        xl[t] = (nbase + n < N) ? xn[(long long)(nbase + n) * HIDDEN + (t & (HIDDEN - 1))]
                                : 0.f;
    }
    __syncthreads();

    float acc[TN];

    // layer 1: h = xn @ W_up + b_up   (K = 256)
    {
        const float bj = b_up[j];
        #pragma unroll
        for (int n = 0; n < TN; n++) acc[n] = bj;
        for (int c = 0; c < HIDDEN; c += 4) {
            const float w0 = W_up[(c + 0) * OUT_EMB + j];
            const float w1 = W_up[(c + 1) * OUT_EMB + j];
            const float w2 = W_up[(c + 2) * OUT_EMB + j];
            const float w3 = W_up[(c + 3) * OUT_EMB + j];
            #pragma unroll
            for (int n = 0; n < TN; n++) {
                const float4 xv = *(const float4*)&xl[n * HIDDEN + c];
                acc[n] += xv.x * w0 + xv.y * w1 + xv.z * w2 + xv.w * w3;
            }
        }
        __syncthreads();
        #pragma unroll
        for (int n = 0; n < TN; n++) hl[n * OUT_EMB + j] = acc[n];
        __syncthreads();
    }

    // layers 2..4: h = silu(h @ W_lins[l] + b_lins[l])   (K = 192)
    for (int l = 0; l < NUM_LAYERS; l++) {
        const float* __restrict__ W = W_lins + (long long)l * OUT_EMB * OUT_EMB;
        const float bj = b_lins[l * OUT_EMB + j];
        #pragma unroll
        for (int n = 0; n < TN; n++) acc[n] = bj;
        for (int c = 0; c < OUT_EMB; c += 4) {
            const float w0 = W[(c + 0) * OUT_EMB + j];
            const float w1 = W[(c + 1) * OUT_EMB + j];
            const float w2 = W[(c + 2) * OUT_EMB + j];
            const float w3 = W[(c + 3) * OUT_EMB + j];
            #pragma unroll
            for (int n = 0; n < TN; n++) {
                const float4 hv = *(const float4*)&hl[n * OUT_EMB + c];
                acc[n] += hv.x * w0 + hv.y * w1 + hv.z * w2 + hv.w * w3;
            }
        }
        __syncthreads();
        #pragma unroll
        for (int n = 0; n < TN; n++) {
            const float a = acc[n];
            hl[n * OUT_EMB + j] = a / (1.f + __expf(-a));   // silu
        }
        __syncthreads();
    }

    // out = h @ W_out   (OUT = 1): thread t < TN handles node nbase+t
    if (j < TN && nbase + j < N) {
        float s = 0.f;
        for (int c = 0; c < OUT_EMB; c++) s += hl[j * OUT_EMB + c] * W_out[c];
        out[nbase + j] = s;
    }
}

extern "C" void kernel_launch(void* const* d_in, const int* in_sizes, int n_in,
                              void* d_out, int out_size, void* d_ws, size_t ws_size,
                              hipStream_t stream) {
    const float* x      = (const float*)d_in[0];
    const float* rbf    = (const float*)d_in[1];
    const int*   idx    = (const int*)d_in[2];
    // d_in[3] = num_nodes scalar (unused; N = out_size since OUT=1)
    const float* W_rbf  = (const float*)d_in[4];
    const float* W_up   = (const float*)d_in[5];
    const float* b_up   = (const float*)d_in[6];
    const float* W_lins = (const float*)d_in[7];
    const float* b_lins = (const float*)d_in[8];
    const float* W_out  = (const float*)d_in[9];
    float* out = (float*)d_out;

    const int E = in_sizes[2];
    const int N = out_size;
    float* xn = (float*)d_ws;  // N*HIDDEN floats = 51.2 MB

    hipMemsetAsync(xn, 0, (size_t)N * HIDDEN * sizeof(float), stream);
    edge_scatter<<<2048, 256, 0, stream>>>(x, rbf, idx, W_rbf, xn, E);
    node_mlp<<<(N + TN - 1) / TN, 192, 0, stream>>>(xn, W_up, b_up, W_lins, b_lins,
                                                    W_out, out, N);
}

// Round 2
// 2154.963 us; speedup vs baseline: 1.9099x; 1.9099x over previous
//
#include <hip/hip_runtime.h>
#include <cmath>

#define HIDDEN 256
#define NUM_RADIAL 6
#define OUT_EMB 192
#define NUM_LAYERS 3
#define TN 32

// ---------- edge path: counting sort by node, then gather ----------

__global__ __launch_bounds__(256) void hist_kernel(const int* __restrict__ idx,
                                                   int* __restrict__ counts, int E) {
    const int e = blockIdx.x * 256 + threadIdx.x;
    if (e < E) atomicAdd(&counts[idx[e]], 1);
}

__global__ __launch_bounds__(1024) void scan_kernel(const int* __restrict__ counts,
                                                    int* __restrict__ start,
                                                    int* __restrict__ cursor,
                                                    int N, int E) {
    __shared__ int pref[1024];
    const int t = threadIdx.x;
    const int chunk = (N + 1023) >> 10;
    const int lo = min(t * chunk, N), hi = min(lo + chunk, N);
    int s = 0;
    for (int i = lo; i < hi; i++) s += counts[i];
    pref[t] = s;
    __syncthreads();
    if (t == 0) {
        int run = 0;
        for (int i = 0; i < 1024; i++) { const int v = pref[i]; pref[i] = run; run += v; }
    }
    __syncthreads();
    int run = pref[t];
    for (int i = lo; i < hi; i++) {
        start[i] = run; cursor[i] = run; run += counts[i];
    }
    if (t == 0) start[N] = E;
}

__global__ __launch_bounds__(256) void perm_kernel(const int* __restrict__ idx,
                                                   int* __restrict__ cursor,
                                                   int* __restrict__ perm, int E) {
    const int e = blockIdx.x * 256 + threadIdx.x;
    if (e < E) {
        const int pos = atomicAdd(&cursor[idx[e]], 1);
        perm[pos] = e;
    }
}

// One block per node, thread = channel. Reads pipeline at full BW; xn written once.
__global__ __launch_bounds__(256) void gather_kernel(
    const float* __restrict__ x, const float* __restrict__ rbf,
    const int* __restrict__ perm, const int* __restrict__ start,
    const float* __restrict__ W_rbf, float* __restrict__ xn, int N)
{
    const int n = blockIdx.x;
    const int c = threadIdx.x;

    float wr[NUM_RADIAL];
    #pragma unroll
    for (int r = 0; r < NUM_RADIAL; r++) wr[r] = W_rbf[r * HIDDEN + c];

    const int p0 = start[n], p1 = start[n + 1];
    float acc = 0.f;
    for (int p = p0; p < p1; p++) {
        const int e = perm[p];
        float g = 0.f;
        #pragma unroll
        for (int r = 0; r < NUM_RADIAL; r++)
            g += wr[r] * rbf[(size_t)e * NUM_RADIAL + r];
        acc += g * x[(size_t)e * HIDDEN + c];
    }
    xn[(size_t)n * HIDDEN + c] = acc;
}

// ---------- node MLP: thread = output column, TN-node tile in LDS ----------
// v2: weights batch-preloaded into 32 registers per c-chunk so 32 loads are in
// flight at once (v1 issued 4 loads per 256 FMA-cycles -> L2-latency-bound).

__global__ __launch_bounds__(192) void node_mlp(
    const float* __restrict__ xn,
    const float* __restrict__ W_up, const float* __restrict__ b_up,
    const float* __restrict__ W_lins, const float* __restrict__ b_lins,
    const float* __restrict__ W_out,
    float* __restrict__ out, int N)
{
    __shared__ float xl[TN * HIDDEN];    // 32 KB
    __shared__ float hl[TN * OUT_EMB];   // 24 KB
    const int j = threadIdx.x;
    const int nbase = blockIdx.x * TN;

    for (int t = j; t < TN * HIDDEN; t += 192) {
        const int n = t / HIDDEN;
        xl[t] = (nbase + n < N) ? xn[(size_t)(nbase + n) * HIDDEN + (t & (HIDDEN - 1))]
                                : 0.f;
    }
    __syncthreads();

    float acc[TN];

    // layer 1: h = xn @ W_up + b_up   (K = 256)
    {
        const float bj = b_up[j];
        #pragma unroll
        for (int n = 0; n < TN; n++) acc[n] = bj;
        for (int c0 = 0; c0 < HIDDEN; c0 += 32) {
            float w[32];
            #pragma unroll
            for (int k = 0; k < 32; k++) w[k] = W_up[(c0 + k) * OUT_EMB + j];
            #pragma unroll
            for (int k = 0; k < 32; k += 4) {
                #pragma unroll
                for (int n = 0; n < TN; n++) {
                    const float4 xv = *(const float4*)&xl[n * HIDDEN + c0 + k];
                    acc[n] += xv.x * w[k] + xv.y * w[k + 1] + xv.z * w[k + 2] + xv.w * w[k + 3];
                }
            }
        }
        __syncthreads();
        #pragma unroll
        for (int n = 0; n < TN; n++) hl[n * OUT_EMB + j] = acc[n];
        __syncthreads();
    }

    // layers 2..4: h = silu(h @ W_lins[l] + b_lins[l])   (K = 192)
    for (int l = 0; l < NUM_LAYERS; l++) {
        const float* __restrict__ W = W_lins + (size_t)l * OUT_EMB * OUT_EMB;
        const float bj = b_lins[l * OUT_EMB + j];
        #pragma unroll
        for (int n = 0; n < TN; n++) acc[n] = bj;
        for (int c0 = 0; c0 < OUT_EMB; c0 += 32) {
            float w[32];
            #pragma unroll
            for (int k = 0; k < 32; k++) w[k] = W[(c0 + k) * OUT_EMB + j];
            #pragma unroll
            for (int k = 0; k < 32; k += 4) {
                #pragma unroll
                for (int n = 0; n < TN; n++) {
                    const float4 hv = *(const float4*)&hl[n * OUT_EMB + c0 + k];
                    acc[n] += hv.x * w[k] + hv.y * w[k + 1] + hv.z * w[k + 2] + hv.w * w[k + 3];
                }
            }
        }
        __syncthreads();
        #pragma unroll
        for (int n = 0; n < TN; n++) {
            const float a = acc[n];
            hl[n * OUT_EMB + j] = a / (1.f + __expf(-a));   // silu
        }
        __syncthreads();
    }

    // out = h @ W_out   (OUT = 1)
    if (j < TN && nbase + j < N) {
        float s = 0.f;
        for (int c = 0; c < OUT_EMB; c++) s += hl[j * OUT_EMB + c] * W_out[c];
        out[nbase + j] = s;
    }
}

extern "C" void kernel_launch(void* const* d_in, const int* in_sizes, int n_in,
                              void* d_out, int out_size, void* d_ws, size_t ws_size,
                              hipStream_t stream) {
    const float* x      = (const float*)d_in[0];
    const float* rbf    = (const float*)d_in[1];
    const int*   idx    = (const int*)d_in[2];
    const float* W_rbf  = (const float*)d_in[4];
    const float* W_up   = (const float*)d_in[5];
    const float* b_up   = (const float*)d_in[6];
    const float* W_lins = (const float*)d_in[7];
    const float* b_lins = (const float*)d_in[8];
    const float* W_out  = (const float*)d_in[9];
    float* out = (float*)d_out;

    const int E = in_sizes[2];
    const int N = out_size;

    // workspace layout
    char* ws = (char*)d_ws;
    float* xn     = (float*)ws;                    ws += (size_t)N * HIDDEN * sizeof(float);
    int*   counts = (int*)ws;                      ws += (size_t)N * sizeof(int);
    int*   start  = (int*)ws;                      ws += (size_t)(N + 1) * sizeof(int);
    int*   cursor = (int*)ws;                      ws += (size_t)N * sizeof(int);
    int*   perm   = (int*)ws;

    hipMemsetAsync(counts, 0, (size_t)N * sizeof(int), stream);
    const int eblocks = (E + 255) / 256;
    hist_kernel<<<eblocks, 256, 0, stream>>>(idx, counts, E);
    scan_kernel<<<1, 1024, 0, stream>>>(counts, start, cursor, N, E);
    perm_kernel<<<eblocks, 256, 0, stream>>>(idx, cursor, perm, E);
    gather_kernel<<<N, 256, 0, stream>>>(x, rbf, perm, start, W_rbf, xn, N);

    node_mlp<<<(N + TN - 1) / TN, 192, 0, stream>>>(xn, W_up, b_up, W_lins, b_lins,
                                                    W_out, out, N);
}